// Round 4
// baseline (222.573 us; speedup 1.0000x reference)
//
#include <hip/hip_runtime.h>
#include <hip/hip_bf16.h>

// Problem config
#define B_     4
#define S_     1024
#define H_     16
#define KVH_   4
#define D_     64
#define N_     (B_*S_)        // 4096
#define SLOTS_ 8192
#define KVD_   (KVH_*D_)      // 256
#define HD_    (H_*D_)        // 1024
#define SCL    (0.125f * 1.44269504f)   // softmax scale * log2(e), folded into Q
#define PSLOT  4160           // floats per partial slot: 4 heads*16*64 + 4*16 lsum

typedef __attribute__((ext_vector_type(8))) short bf16x8;
typedef __attribute__((ext_vector_type(4))) short bf16x4;
typedef __attribute__((ext_vector_type(4))) float f32x4;

// 64-col LDS tile with XOR swizzle; index in shorts.
__device__ __forceinline__ int swz(int row, int col){
    return row*64 + (col ^ ((row & 7) << 3));
}
__device__ __forceinline__ short4 f4tob4(float4 f){
    union { __hip_bfloat162 h[2]; short4 s; } u;
    u.h[0] = __float22bfloat162_rn(make_float2(f.x, f.y));
    u.h[1] = __float22bfloat162_rn(make_float2(f.z, f.w));
    return u.s;
}

// ---------------------------------------------------------------------------
// KV-cache fill via inverse map
// ---------------------------------------------------------------------------
__global__ void inv_init(int* __restrict__ inv){
    inv[blockIdx.x*256 + threadIdx.x] = -1;
}
__global__ void inv_scatter(const int* __restrict__ slot, int* __restrict__ inv){
    int i = blockIdx.x*256 + threadIdx.x;
    int s = slot[i];
    if (s >= 0 && s < SLOTS_) inv[s] = i;
}
__global__ void cache_fill(const float4* __restrict__ kin, const float4* __restrict__ vin,
                           const float4* __restrict__ kcin, const float4* __restrict__ vcin,
                           const int* __restrict__ inv,
                           float4* __restrict__ kc, float4* __restrict__ vc){
    int i = blockIdx.x*256 + threadIdx.x;
    int row = i >> 6, c = i & 63;
    int n = inv[row];                      // wave-uniform (64 threads per row... 2 rows/wave)
    if (n >= 0){
        kc[i] = kin[(size_t)n*64 + c];
        vc[i] = vin[(size_t)n*64 + c];
    } else {
        kc[i] = kcin[i];
        vc[i] = vcin[i];
    }
}

// ---------------------------------------------------------------------------
// Flash attention, causal, GQA, static-max softmax, KEY-PARTITIONED.
// Block = (g, qt, c): kv-group g (4 heads = 4 waves), 16-row q-tile qt,
// key-chunk c of TC 64-key tiles. Chunks with no work exit immediately.
// Single-chunk q-tiles write o directly; otherwise unnormalized partials +
// row-sums go to opart and combine_kernel finishes (sums are exact: static
// max makes partials additive).
// ---------------------------------------------------------------------------
__global__ __launch_bounds__(256, 6) void attn_kernel(
    const float* __restrict__ q, const float* __restrict__ k,
    const float* __restrict__ v, float* __restrict__ o,
    float* __restrict__ opart, int TC, int NCshift)
{
    __shared__ __align__(16) short sK[64*64];   // [key][dim] swizzled
    __shared__ __align__(16) short sV[64*64];   // [dim][key] swizzled
#if !(defined(__has_builtin) && __has_builtin(__builtin_amdgcn_mfma_f32_16x16x16bf16_1k))
    __shared__ __align__(16) short sP[4][16*64];
#endif

    const int g  = blockIdx.x >> (6 + NCshift);
    const int qt = (blockIdx.x >> NCshift) & 63;
    const int c  = blockIdx.x & ((1 << NCshift) - 1);

    const int ntiles = (qt >> 2) + 1;
    const int t0 = c * TC;
    if (t0 >= ntiles) return;                   // uniform exit, before any barrier
    const int t1 = min(t0 + TC, ntiles);
    const bool direct = (ntiles <= TC);         // only c==0 reaches here then

    const int tid  = threadIdx.x;
    const int wave = tid >> 6;
    const int lane = tid & 63;
    const int quad = lane >> 4;
    const int l16  = lane & 15;

    const int kvh = g & 3;
    const int b   = g >> 2;
    const int h   = kvh*4 + wave;
    const int q0  = qt * 16;

    // ---- Q fragments (per-lane layout shared by A and B: row=l16, k=quad*8+j)
    bf16x8 qf[2];
    {
        const float* qp = q + ((size_t)(b*S_ + q0 + l16))*HD_ + h*D_ + quad*8;
        #pragma unroll
        for (int ks = 0; ks < 2; ++ks){
            float4 a0 = *(const float4*)(qp + ks*32);
            float4 a1 = *(const float4*)(qp + ks*32 + 4);
            a0.x*=SCL; a0.y*=SCL; a0.z*=SCL; a0.w*=SCL;
            a1.x*=SCL; a1.y*=SCL; a1.z*=SCL; a1.w*=SCL;
            union { short4 s[2]; bf16x8 v8; } u;
            u.s[0] = f4tob4(a0); u.s[1] = f4tob4(a1);
            qf[ks] = u.v8;
        }
    }

    f32x4 of[4];
    #pragma unroll
    for (int f2 = 0; f2 < 4; ++f2) of[f2] = (f32x4){0.f,0.f,0.f,0.f};
    float lsum = 0.f;                      // row-sum for q = q0 + l16

    // ---- staging: thread owns keys (t*64 + 4*rr + p), dims c4..c4+3
    const int rr = tid >> 4;
    const int c4 = (tid & 15) * 4;
    const float* kb_p = k + ((size_t)(b*S_ + 4*rr))*KVD_ + kvh*D_ + c4;
    const float* vb_p = v + ((size_t)(b*S_ + 4*rr))*KVD_ + kvh*D_ + c4;

    // raw float4 prefetch (convert at write time so vmcnt-wait lands post-barrier)
    float4 kreg[4], vreg[4];
    #pragma unroll
    for (int p = 0; p < 4; ++p){
        kreg[p] = *(const float4*)(kb_p + (size_t)(t0*64 + p)*KVD_);
        vreg[p] = *(const float4*)(vb_p + (size_t)(t0*64 + p)*KVD_);
    }

    #pragma unroll 1
    for (int t = t0; t < t1; ++t){
        if (t > t0) __syncthreads();       // reads of previous tile complete

        // convert + write LDS: K row-major b64, V transposed b64
        short4 ks4[4], vs4[4];
        #pragma unroll
        for (int p = 0; p < 4; ++p){ ks4[p] = f4tob4(kreg[p]); vs4[p] = f4tob4(vreg[p]); }
        #pragma unroll
        for (int p = 0; p < 4; ++p)
            *(short4*)(&sK[swz(4*rr + p, c4)]) = ks4[p];
        *(short4*)(&sV[swz(c4+0, 4*rr)]) = make_short4(vs4[0].x, vs4[1].x, vs4[2].x, vs4[3].x);
        *(short4*)(&sV[swz(c4+1, 4*rr)]) = make_short4(vs4[0].y, vs4[1].y, vs4[2].y, vs4[3].y);
        *(short4*)(&sV[swz(c4+2, 4*rr)]) = make_short4(vs4[0].z, vs4[1].z, vs4[2].z, vs4[3].z);
        *(short4*)(&sV[swz(c4+3, 4*rr)]) = make_short4(vs4[0].w, vs4[1].w, vs4[2].w, vs4[3].w);

        if (t + 1 < t1){
            #pragma unroll
            for (int p = 0; p < 4; ++p){
                kreg[p] = *(const float4*)(kb_p + (size_t)((t+1)*64 + p)*KVD_);
                vreg[p] = *(const float4*)(vb_p + (size_t)((t+1)*64 + p)*KVD_);
            }
        }
        __syncthreads();                   // staged tile visible

        // ---- S^T = K Q^T : lane holds S[q=l16][key = t*64 + f*16 + quad*4 + r]
        f32x4 sc[4];
        #pragma unroll
        for (int f = 0; f < 4; ++f) sc[f] = (f32x4){0.f,0.f,0.f,0.f};
        #pragma unroll
        for (int ks = 0; ks < 2; ++ks){
            #pragma unroll
            for (int f = 0; f < 4; ++f){
                bf16x8 kf = *(const bf16x8*)(&sK[swz(f*16 + l16, ks*32 + quad*8)]);
                sc[f] = __builtin_amdgcn_mfma_f32_16x16x32_bf16(kf, qf[ks], sc[f], 0, 0, 0);
            }
        }

        const bool diag = (t == ntiles - 1);
        const int  kb   = t*64;
        const int  qrow = q0 + l16;
#if defined(__has_builtin) && __has_builtin(__builtin_amdgcn_mfma_f32_16x16x16bf16_1k)
        bf16x4 pfrag[4];
        #pragma unroll
        for (int f = 0; f < 4; ++f){
            float4 pf;
            #pragma unroll
            for (int r = 0; r < 4; ++r){
                float p = __builtin_amdgcn_exp2f(sc[f][r]);
                if (diag && (kb + f*16 + quad*4 + r > qrow)) p = 0.f;
                lsum += p;
                ((float*)&pf)[r] = p;
            }
            union { short4 s; bf16x4 bv; } u; u.s = f4tob4(pf);
            pfrag[f] = u.bv;
        }
        #pragma unroll
        for (int f = 0; f < 4; ++f){
            #pragma unroll
            for (int f2 = 0; f2 < 4; ++f2){
                bf16x4 vf = *(const bf16x4*)(&sV[swz(f2*16 + l16, f*16 + quad*4)]);
                of[f2] = __builtin_amdgcn_mfma_f32_16x16x16bf16_1k(pfrag[f], vf, of[f2], 0, 0, 0);
            }
        }
#else
        #pragma unroll
        for (int f = 0; f < 4; ++f){
            #pragma unroll
            for (int r = 0; r < 4; ++r){
                float p = __builtin_amdgcn_exp2f(sc[f][r]);
                if (diag && (kb + f*16 + quad*4 + r > qrow)) p = 0.f;
                lsum += p;
                __hip_bfloat16 hb = __float2bfloat16(p);
                sP[wave][swz(l16, f*16 + quad*4 + r)] = *reinterpret_cast<short*>(&hb);
            }
        }
        #pragma unroll
        for (int ks = 0; ks < 2; ++ks){
            bf16x8 pa = *(const bf16x8*)(&sP[wave][swz(l16, ks*32 + quad*8)]);
            #pragma unroll
            for (int f2 = 0; f2 < 4; ++f2){
                bf16x8 vf = *(const bf16x8*)(&sV[swz(f2*16 + l16, ks*32 + quad*8)]);
                of[f2] = __builtin_amdgcn_mfma_f32_16x16x32_bf16(pa, vf, of[f2], 0, 0, 0);
            }
        }
#endif
    }

    // ---- row-sum across quads (all lanes end with total for q = q0+l16)
    lsum += __shfl_xor(lsum, 16);
    lsum += __shfl_xor(lsum, 32);

    if (direct){
        float linv[4];
        #pragma unroll
        for (int r = 0; r < 4; ++r)
            linv[r] = 1.f / __shfl(lsum, quad*4 + r);
        #pragma unroll
        for (int f2 = 0; f2 < 4; ++f2){
            #pragma unroll
            for (int r = 0; r < 4; ++r){
                const int row = q0 + quad*4 + r;
                o[((size_t)(b*S_ + row))*HD_ + h*D_ + f2*16 + l16] = of[f2][r] * linv[r];
            }
        }
    } else {
        const size_t slot = ((size_t)(g*64 + qt) << NCshift) + c;
        float* Ob = opart + slot*PSLOT;
        #pragma unroll
        for (int f2 = 0; f2 < 4; ++f2){
            #pragma unroll
            for (int r = 0; r < 4; ++r)
                Ob[wave*1024 + (quad*4 + r)*64 + f2*16 + l16] = of[f2][r];
        }
        if (quad == 0)
            Ob[4096 + wave*16 + l16] = lsum;
    }
}

// ---------------------------------------------------------------------------
// Combine partial chunks: o = (sum_c O_c) / (sum_c l_c). One block per (g, qt)
// with >1 chunk. thread = (head,row) pair x dim-quarter.
// ---------------------------------------------------------------------------
__global__ __launch_bounds__(256) void combine_kernel(
    const float* __restrict__ opart, float* __restrict__ o,
    int TC, int NCshift, int nqt)
{
    const int bid = blockIdx.x;
    const int g   = bid / nqt;
    const int qt  = 4*TC + (bid % nqt);
    const int nc  = (qt >> 2)/TC + 1;         // ceil(ntiles/TC)

    const int tpr  = threadIdx.x >> 2;        // 0..63
    const int head = tpr >> 4;
    const int row  = tpr & 15;
    const int dq   = threadIdx.x & 3;

    float acc[16];
    #pragma unroll
    for (int j = 0; j < 16; ++j) acc[j] = 0.f;
    float lacc = 0.f;

    for (int cc = 0; cc < nc; ++cc){
        const size_t slot = ((size_t)(g*64 + qt) << NCshift) + cc;
        const float* Ob = opart + slot*PSLOT;
        const float4* src = (const float4*)(Ob + head*1024 + row*64 + dq*16);
        #pragma unroll
        for (int j4 = 0; j4 < 4; ++j4){
            float4 s4 = src[j4];
            acc[j4*4+0] += s4.x; acc[j4*4+1] += s4.y;
            acc[j4*4+2] += s4.z; acc[j4*4+3] += s4.w;
        }
        lacc += Ob[4096 + head*16 + row];
    }
    const float linv = 1.f / lacc;

    const int b = g >> 2, kvh = g & 3, h = kvh*4 + head;
    float* dst = o + ((size_t)(b*S_ + qt*16 + row))*HD_ + h*D_ + dq*16;
    #pragma unroll
    for (int j4 = 0; j4 < 4; ++j4){
        float4 d4 = make_float4(acc[j4*4+0]*linv, acc[j4*4+1]*linv,
                                acc[j4*4+2]*linv, acc[j4*4+3]*linv);
        ((float4*)dst)[j4] = d4;
    }
}

// ---------------------------------------------------------------------------
extern "C" void kernel_launch(void* const* d_in, const int* in_sizes, int n_in,
                              void* d_out, int out_size, void* d_ws, size_t ws_size,
                              hipStream_t stream){
    (void)in_sizes; (void)n_in; (void)out_size;
    const float* q     = (const float*)d_in[0];
    const float* k     = (const float*)d_in[1];
    const float* v     = (const float*)d_in[2];
    const float* kc_in = (const float*)d_in[3];
    const float* vc_in = (const float*)d_in[4];
    const int*   slot  = (const int*)d_in[5];

    float* o  = (float*)d_out;
    float* kc = o + (size_t)N_*HD_;
    float* vc = kc + (size_t)SLOTS_*KVD_;

    int*   inv   = (int*)d_ws;                              // [SLOTS_] = 32 KB
    float* opart = (float*)((char*)d_ws + 32768);

    // adaptive chunk size per available workspace (deterministic across calls)
    const size_t slot_bytes = (size_t)PSLOT * 4;
    int TC, NCshift;
    if      (ws_size >= 32768 + ((size_t)1024 << 2) * slot_bytes){ TC = 4;  NCshift = 2; }
    else if (ws_size >= 32768 + ((size_t)1024 << 1) * slot_bytes){ TC = 8;  NCshift = 1; }
    else                                                          { TC = 16; NCshift = 0; }

    attn_kernel<<<1024 << NCshift, 256, 0, stream>>>(q, k, v, o, opart, TC, NCshift);

    const int nqt = 64 - 4*TC;
    if (nqt > 0)
        combine_kernel<<<16*nqt, 256, 0, stream>>>(opart, o, TC, NCshift, nqt);

    inv_init<<<SLOTS_/256, 256, 0, stream>>>(inv);
    inv_scatter<<<N_/256, 256, 0, stream>>>(slot, inv);
    cache_fill<<<(SLOTS_*(KVD_/4))/256, 256, 0, stream>>>(
        (const float4*)k, (const float4*)v,
        (const float4*)kc_in, (const float4*)vc_in, inv,
        (float4*)kc, (float4*)vc);
}